// Round 5
// baseline (1031.149 us; speedup 1.0000x reference)
//
#include <hip/hip_runtime.h>
#include <hip/hip_bf16.h>

typedef unsigned short u16;
typedef unsigned int u32;

#define HDIM 64
#define EPS 1e-5f
#define TILE 256           // nodes per block (phase1)
#define ZSTRIDE 68         // u16 stride (8B-aligned rows, bank-friendly)

// ---------- helpers ----------

__device__ __forceinline__ float wave_sum64(float v) {
    v += __shfl_xor(v, 1, 64);
    v += __shfl_xor(v, 2, 64);
    v += __shfl_xor(v, 4, 64);
    v += __shfl_xor(v, 8, 64);
    v += __shfl_xor(v, 16, 64);
    v += __shfl_xor(v, 32, 64);
    return v;
}

__device__ __forceinline__ float bcast(float v, int k) {
    return __int_as_float(__builtin_amdgcn_readlane(__float_as_int(v), k));
}

// round-to-nearest-even f32 -> bf16 bits
__device__ __forceinline__ u16 f2bf(float f) {
    u32 u = __float_as_uint(f);
    u32 r = (u + 0x7fffu + ((u >> 16) & 1u)) >> 16;
    return (u16)r;
}

// ---------- phase 1: tiled per-node transform -> bf16 tables ----------
// 256-node tile per block. LN'd activations staged bf16 in LDS; one 64x64
// weight in LDS at a time. Each thread owns an 8-node x 8-h register tile
// (64 acc regs; peak live ~100 VGPR -> no spill, unlike node-per-lane).
__global__ __launch_bounds__(256) void phase1_kernel(
    const float* __restrict__ z,
    const float* __restrict__ root_w, const float* __restrict__ root_b,
    const float* __restrict__ lin1_w, const float* __restrict__ lin1_b,
    const float* __restrict__ lin2_w, const float* __restrict__ lin2_b,
    const float* __restrict__ bil_w,
    const float* __restrict__ norm_g, const float* __restrict__ norm_b,
    u16* __restrict__ T1, u16* __restrict__ T2, int nnodes)
{
    __shared__ u16   Zs[TILE * ZSTRIDE];     // 34.8 KB, bf16 activations
    __shared__ float WLDS[4096];             // 16 KB, one weight matrix
    __shared__ float gbuf[64], bbuf[64], b1buf[64], b2buf[64];

    const int tid = threadIdx.x;
    const int n0  = blockIdx.x * TILE;

    if (tid < 64) {
        gbuf[tid]  = norm_g[tid];
        bbuf[tid]  = norm_b[tid];
        b1buf[tid] = lin1_b[tid];
        b2buf[tid] = lin2_b[tid];
    }

    // ---- stage 0: load z rows, LN, write bf16 to Zs (2 threads/node) ----
    // also stage W2 (transposed) into WLDS; both precede one barrier.
    {
        const int half = tid & 1;            // which 32-elem half
#pragma unroll
        for (int p = 0; p < 2; ++p) {
            const int nl = p * 128 + (tid >> 1);      // local node
            const int n  = n0 + nl;                   // global node
            float r[32];
            if (n == 0) {
#pragma unroll
                for (int j = 0; j < 32; ++j) {
                    const int k = half * 32 + j;
                    r[j] = root_w[k] + root_b[k];
                }
            } else if (n < nnodes) {
                const float4* zp =
                    (const float4*)(z + (size_t)(n - 1) * HDIM + half * 32);
#pragma unroll
                for (int q = 0; q < 8; ++q) {
                    float4 v = zp[q];
                    r[4*q] = v.x; r[4*q+1] = v.y; r[4*q+2] = v.z; r[4*q+3] = v.w;
                }
            } else {
#pragma unroll
                for (int j = 0; j < 32; ++j) r[j] = 0.f;
            }
            float s = 0.f, sq = 0.f;
#pragma unroll
            for (int j = 0; j < 32; ++j) { s += r[j]; sq = fmaf(r[j], r[j], sq); }
            s  += __shfl_xor(s, 1, 64);     // partner thread (same node)
            sq += __shfl_xor(sq, 1, 64);
            const float mu = s * 0.015625f;
            const float rs = rsqrtf(sq * 0.015625f - mu * mu + EPS);
            // normalize + pack bf16, write 8 x uint2 (8B aligned: 136r+64c+8j)
            u16 tmp[32];
#pragma unroll
            for (int j = 0; j < 32; ++j) {
                const int k = half * 32 + j;
                tmp[j] = f2bf((r[j] - mu) * rs * gbuf[k] + bbuf[k]);
            }
            u16* dst = &Zs[nl * ZSTRIDE + half * 32];
#pragma unroll
            for (int j = 0; j < 8; ++j)
                *(uint2*)&dst[4*j] = *(uint2*)&tmp[4*j];
        }
        // stage W2t: WLDS[k*64+h] = lin2_w[h*64+k]
        for (int i = tid; i < 4096; i += 256) {
            const int k = i >> 6, h = i & 63;
            WLDS[i] = lin2_w[(h << 6) | k];
        }
    }
    __syncthreads();

    const int hh = tid & 7;          // h-group: h0..h0+7
    const int h0 = hh << 3;
    const int g  = tid >> 3;         // node-group: nodes g+32m

    float acc[8][8];

    // GEMM macro: acc[m][j] (+)= Zs_row(g+32m) @ WLDS, bf16 A, f32 W
#define GEMM_TILE() do {                                                \
    _Pragma("unroll")                                                   \
    for (int kb = 0; kb < 64; kb += 4) {                                \
        uint2 zb[8];                                                    \
        _Pragma("unroll")                                               \
        for (int m = 0; m < 8; ++m)                                     \
            zb[m] = *(const uint2*)&Zs[(g + 32*m) * ZSTRIDE + kb];      \
        _Pragma("unroll")                                               \
        for (int j = 0; j < 4; ++j) {                                   \
            const float4 wA = *(const float4*)&WLDS[(kb + j)*64 + h0];      \
            const float4 wB = *(const float4*)&WLDS[(kb + j)*64 + h0 + 4];  \
            _Pragma("unroll")                                           \
            for (int m = 0; m < 8; ++m) {                               \
                const u32 word = (j < 2) ? zb[m].x : zb[m].y;           \
                const float s = __uint_as_float(                        \
                    (j & 1) ? (word & 0xffff0000u) : (word << 16));     \
                acc[m][0] = fmaf(s, wA.x, acc[m][0]);                   \
                acc[m][1] = fmaf(s, wA.y, acc[m][1]);                   \
                acc[m][2] = fmaf(s, wA.z, acc[m][2]);                   \
                acc[m][3] = fmaf(s, wA.w, acc[m][3]);                   \
                acc[m][4] = fmaf(s, wB.x, acc[m][4]);                   \
                acc[m][5] = fmaf(s, wB.y, acc[m][5]);                   \
                acc[m][6] = fmaf(s, wB.z, acc[m][6]);                   \
                acc[m][7] = fmaf(s, wB.w, acc[m][7]);                   \
            }                                                           \
        }                                                               \
    }                                                                   \
} while (0)

    // relu + LN over h (8 regs x 8 lanes), in place on acc
#define RELU_LN() do {                                                  \
    const float4 gA = *(const float4*)&gbuf[h0];                        \
    const float4 gB = *(const float4*)&gbuf[h0 + 4];                    \
    const float4 bA = *(const float4*)&bbuf[h0];                        \
    const float4 bB = *(const float4*)&bbuf[h0 + 4];                    \
    _Pragma("unroll")                                                   \
    for (int m = 0; m < 8; ++m) {                                       \
        float s_ = 0.f, sq_ = 0.f;                                      \
        _Pragma("unroll")                                               \
        for (int j = 0; j < 8; ++j) {                                   \
            acc[m][j] = fmaxf(acc[m][j], 0.f);                          \
            s_ += acc[m][j]; sq_ = fmaf(acc[m][j], acc[m][j], sq_);     \
        }                                                               \
        s_  += __shfl_xor(s_, 1, 64);  sq_ += __shfl_xor(sq_, 1, 64);   \
        s_  += __shfl_xor(s_, 2, 64);  sq_ += __shfl_xor(sq_, 2, 64);   \
        s_  += __shfl_xor(s_, 4, 64);  sq_ += __shfl_xor(sq_, 4, 64);   \
        const float mu_ = s_ * 0.015625f;                               \
        const float rs_ = rsqrtf(sq_ * 0.015625f - mu_ * mu_ + EPS);    \
        acc[m][0] = (acc[m][0]-mu_)*rs_*gA.x + bA.x;                    \
        acc[m][1] = (acc[m][1]-mu_)*rs_*gA.y + bA.y;                    \
        acc[m][2] = (acc[m][2]-mu_)*rs_*gA.z + bA.z;                    \
        acc[m][3] = (acc[m][3]-mu_)*rs_*gA.w + bA.w;                    \
        acc[m][4] = (acc[m][4]-mu_)*rs_*gB.x + bB.x;                    \
        acc[m][5] = (acc[m][5]-mu_)*rs_*gB.y + bB.y;                    \
        acc[m][6] = (acc[m][6]-mu_)*rs_*gB.z + bB.z;                    \
        acc[m][7] = (acc[m][7]-mu_)*rs_*gB.w + bB.w;                    \
    }                                                                   \
} while (0)

    // ---- branch 2: x2 = LN(relu(Zs@W2t + b2)) -> T2 ----
    {
        const float4 iA = *(const float4*)&b2buf[h0];
        const float4 iB = *(const float4*)&b2buf[h0 + 4];
#pragma unroll
        for (int m = 0; m < 8; ++m) {
            acc[m][0]=iA.x; acc[m][1]=iA.y; acc[m][2]=iA.z; acc[m][3]=iA.w;
            acc[m][4]=iB.x; acc[m][5]=iB.y; acc[m][6]=iB.z; acc[m][7]=iB.w;
        }
    }
    GEMM_TILE();
    RELU_LN();
#pragma unroll
    for (int m = 0; m < 8; ++m) {
        const int n = n0 + g + 32*m;
        if (n < nnodes) {
            u16 tmp[8];
#pragma unroll
            for (int j = 0; j < 8; ++j) tmp[j] = f2bf(acc[m][j]);
            *(uint4*)(T2 + (size_t)n * HDIM + h0) = *(uint4*)tmp;   // 16B aligned
        }
    }
    __syncthreads();                       // WLDS rewrite safe

    // ---- branch 1 matmul: stage W1t, GEMM, relu+LN ----
    for (int i = tid; i < 4096; i += 256) {
        const int k = i >> 6, h = i & 63;
        WLDS[i] = lin1_w[(h << 6) | k];
    }
    __syncthreads();
    {
        const float4 iA = *(const float4*)&b1buf[h0];
        const float4 iB = *(const float4*)&b1buf[h0 + 4];
#pragma unroll
        for (int m = 0; m < 8; ++m) {
            acc[m][0]=iA.x; acc[m][1]=iA.y; acc[m][2]=iA.z; acc[m][3]=iA.w;
            acc[m][4]=iB.x; acc[m][5]=iB.y; acc[m][6]=iB.z; acc[m][7]=iB.w;
        }
    }
    GEMM_TILE();
    RELU_LN();
    __syncthreads();                       // everyone done reading Zs/WLDS

    // ---- write x1 (bf16) into Zs; stage bil_w into WLDS ----
#pragma unroll
    for (int m = 0; m < 8; ++m) {
        u16 tmp[8];
#pragma unroll
        for (int j = 0; j < 8; ++j) tmp[j] = f2bf(acc[m][j]);
        u16* dst = &Zs[(g + 32*m) * ZSTRIDE + h0];    // byte 136n+16hh: 8B-aligned
        *(uint2*)&dst[0] = *(uint2*)&tmp[0];
        *(uint2*)&dst[4] = *(uint2*)&tmp[4];
    }
    for (int i = tid; i < 4096; i += 256)
        WLDS[i] = bil_w[i];                // B[h][g] row-major, no transpose
    __syncthreads();

    // ---- t = x1 @ B -> T1 ----
#pragma unroll
    for (int m = 0; m < 8; ++m)
#pragma unroll
        for (int j = 0; j < 8; ++j) acc[m][j] = 0.f;
    GEMM_TILE();
#pragma unroll
    for (int m = 0; m < 8; ++m) {
        const int n = n0 + g + 32*m;
        if (n < nnodes) {
            u16 tmp[8];
#pragma unroll
            for (int j = 0; j < 8; ++j) tmp[j] = f2bf(acc[m][j]);
            *(uint4*)(T1 + (size_t)n * HDIM + h0) = *(uint4*)tmp;
        }
    }
#undef GEMM_TILE
#undef RELU_LN
}

// ---------- phase 2: per-edge gather + 64-dot ----------
__global__ __launch_bounds__(256) void phase2_kernel(
    const int* __restrict__ arcs,
    const u16* __restrict__ T1, const u16* __restrict__ T2,
    const float* __restrict__ bil_b,
    float* __restrict__ out, int E)
{
    const int tid = blockIdx.x * 256 + threadIdx.x;
    const int e = tid >> 3;
    if (e >= E) return;
    const int l8 = tid & 7;

    const int i0 = arcs[2 * e];
    const int i1 = arcs[2 * e + 1];

    const uint4* p1 = (const uint4*)(T1 + (size_t)i0 * HDIM) + l8;
    const uint4* p2 = (const uint4*)(T2 + (size_t)i1 * HDIM) + l8;
    uint4 u = *p1;
    uint4 v = *p2;

    float s = 0.f;
    {
        u32 ua[4] = {u.x, u.y, u.z, u.w};
        u32 va[4] = {v.x, v.y, v.z, v.w};
#pragma unroll
        for (int i = 0; i < 4; ++i) {
            float alo = __uint_as_float(ua[i] << 16);
            float ahi = __uint_as_float(ua[i] & 0xffff0000u);
            float blo = __uint_as_float(va[i] << 16);
            float bhi = __uint_as_float(va[i] & 0xffff0000u);
            s = fmaf(alo, blo, s);
            s = fmaf(ahi, bhi, s);
        }
    }
    s += __shfl_xor(s, 1, 64);
    s += __shfl_xor(s, 2, 64);
    s += __shfl_xor(s, 4, 64);
    if (l8 == 0) out[e] = s + bil_b[0];
}

// ---------- fallback: per-edge full recompute (if ws too small) ----------
__device__ __forceinline__ float lnorm_w(float v, float g, float b) {
    float mu = wave_sum64(v) * 0.015625f;
    float d  = v - mu;
    float var = wave_sum64(d * d) * 0.015625f;
    return d * rsqrtf(var + EPS) * g + b;
}

__global__ __launch_bounds__(256) void edge_direct_kernel(
    const float* __restrict__ z, const int* __restrict__ arcs,
    const float* __restrict__ root_w, const float* __restrict__ root_b,
    const float* __restrict__ lin1_w, const float* __restrict__ lin1_b,
    const float* __restrict__ lin2_w, const float* __restrict__ lin2_b,
    const float* __restrict__ bil_w, const float* __restrict__ bil_b,
    const float* __restrict__ norm_g, const float* __restrict__ norm_b,
    float* __restrict__ out, int E, int nnodes)
{
    __shared__ float W1t[4096], W2t[4096], Bs[4096];
    const int tid = threadIdx.x;
    for (int i = tid; i < 4096; i += 256) {
        int h = i >> 6, k = i & 63;
        W1t[(k << 6) | h] = lin1_w[i];
        W2t[(k << 6) | h] = lin2_w[i];
        Bs[i] = bil_w[i];
    }
    __syncthreads();

    const int lane = tid & 63;
    const float g  = norm_g[lane], bt = norm_b[lane];
    const float b1 = lin1_b[lane], b2 = lin2_b[lane];
    const float rootv = root_w[lane] + root_b[lane];

    const int gwave = (blockIdx.x * 256 + tid) >> 6;
    const int nwaves = (gridDim.x * 256) >> 6;

    for (int e = gwave; e < E; e += nwaves) {
        int i0 = arcs[2 * e], i1 = arcs[2 * e + 1];
        float v0 = (i0 == 0) ? rootv : z[(size_t)(i0 - 1) * HDIM + lane];
        float v1 = (i1 == 0) ? rootv : z[(size_t)(i1 - 1) * HDIM + lane];
        float l0 = lnorm_w(v0, g, bt);
        float l1 = lnorm_w(v1, g, bt);
        float a1 = 0.f, a2 = 0.f;
#pragma unroll
        for (int k = 0; k < 64; ++k) {
            a1 = fmaf(bcast(l0, k), W1t[(k << 6) | lane], a1);
            a2 = fmaf(bcast(l1, k), W2t[(k << 6) | lane], a2);
        }
        float x1 = lnorm_w(fmaxf(a1 + b1, 0.f), g, bt);
        float x2 = lnorm_w(fmaxf(a2 + b2, 0.f), g, bt);
        float w1 = 0.f;
#pragma unroll
        for (int h = 0; h < 64; ++h)
            w1 = fmaf(bcast(x1, h), Bs[(h << 6) | lane], w1);
        float sc = wave_sum64(w1 * x2);
        if (lane == 0) out[e] = sc + bil_b[0];
    }
}

// ---------- launch ----------
extern "C" void kernel_launch(void* const* d_in, const int* in_sizes, int n_in,
                              void* d_out, int out_size, void* d_ws, size_t ws_size,
                              hipStream_t stream) {
    const float* z      = (const float*)d_in[0];
    const int*   arcs   = (const int*)  d_in[1];
    const float* root_w = (const float*)d_in[2];
    const float* root_b = (const float*)d_in[3];
    const float* lin1_w = (const float*)d_in[4];
    const float* lin1_b = (const float*)d_in[5];
    const float* lin2_w = (const float*)d_in[6];
    const float* lin2_b = (const float*)d_in[7];
    const float* bil_w  = (const float*)d_in[8];
    const float* bil_b  = (const float*)d_in[9];
    const float* norm_g = (const float*)d_in[10];
    const float* norm_b = (const float*)d_in[11];
    float* out = (float*)d_out;

    const int E      = in_sizes[1] / 2;
    const int nnodes = in_sizes[0] / HDIM + 1;

    const size_t tbl  = (size_t)nnodes * HDIM * sizeof(u16);
    const size_t need = 2 * tbl;

    if (ws_size >= need) {
        u16* T1 = (u16*)d_ws;
        u16* T2 = (u16*)((char*)d_ws + tbl);

        const int blocks1 = (nnodes + TILE - 1) / TILE;
        phase1_kernel<<<blocks1, 256, 0, stream>>>(
            z, root_w, root_b, lin1_w, lin1_b, lin2_w, lin2_b,
            bil_w, norm_g, norm_b, T1, T2, nnodes);

        const long long thr2 = (long long)E * 8;
        const int blocks2 = (int)((thr2 + 255) / 256);
        phase2_kernel<<<blocks2, 256, 0, stream>>>(arcs, T1, T2, bil_b, out, E);
    } else {
        edge_direct_kernel<<<8192, 256, 0, stream>>>(
            z, arcs, root_w, root_b, lin1_w, lin1_b, lin2_w, lin2_b,
            bil_w, bil_b, norm_g, norm_b, out, E, nnodes);
    }
}

// Round 7
// 183.390 us; speedup vs baseline: 5.6227x; 5.6227x over previous
//
#include <hip/hip_runtime.h>
#include <hip/hip_bf16.h>

typedef unsigned short u16;
typedef unsigned int u32;

#define HDIM 64
#define EPS 1e-5f
#define ZROW 33      // u32 stride per node row in LDS: 2-way bank alias only

// ---------- helpers ----------

__device__ __forceinline__ float wave_sum64(float v) {
    v += __shfl_xor(v, 1, 64);
    v += __shfl_xor(v, 2, 64);
    v += __shfl_xor(v, 4, 64);
    v += __shfl_xor(v, 8, 64);
    v += __shfl_xor(v, 16, 64);
    v += __shfl_xor(v, 32, 64);
    return v;
}

__device__ __forceinline__ float bcast(float v, int k) {
    return __int_as_float(__builtin_amdgcn_readlane(__float_as_int(v), k));
}

// round-to-nearest-even f32 -> bf16 bits
__device__ __forceinline__ u16 f2bf(float f) {
    u32 u = __float_as_uint(f);
    u32 r = (u + 0x7fffu + ((u >> 16) & 1u)) >> 16;
    return (u16)r;
}

__device__ __forceinline__ u32 pack2(float e0, float e1) {
    return (u32)f2bf(e0) | ((u32)f2bf(e1) << 16);
}
__device__ __forceinline__ float bflo(u32 w) { return __uint_as_float(w << 16); }
__device__ __forceinline__ float bfhi(u32 w) { return __uint_as_float(w & 0xffff0000u); }

// ---------- weight transpose (once, tiny) ----------
__global__ __launch_bounds__(256) void transpose_w_kernel(
    const float* __restrict__ lin1_w, const float* __restrict__ lin2_w,
    float* __restrict__ wt1, float* __restrict__ wt2)
{
    const int tid = threadIdx.x;
    for (int i = tid; i < 4096; i += 256) {
        const int h = i >> 6, k = i & 63;
        wt1[k * 64 + h] = lin1_w[i];
        wt2[k * 64 + h] = lin2_w[i];
    }
}

// ---------- phase 1 ----------
// Node-per-thread. LN'd row packed bf16 in a PRIVATE LDS row (indexable
// scratch; no cross-thread use, no barriers). Weights = wave-uniform global
// reads (s_load/broadcast; pre-transposed). Output h in 16-chunks, rolled
// k-loop. Peak live regs ~60 -> spill structurally impossible.

// y[h] = [bias[h] +] sum_k in[k] * W[k*64+h]; optional relu; bf16-pack into
// OUTP[32]; f32 stats of (relu'd) values into OSUM/OSQ.
#define MATMUL(WPTR, BIASPTR, DO_RELU, OUTP, OSUM, OSQ) do {                \
    float osum_ = 0.f, osq_ = 0.f;                                          \
    _Pragma("unroll")                                                       \
    for (int hc_ = 0; hc_ < 4; ++hc_) {                                     \
        const int h0_ = hc_ * 16;                                           \
        float acc_[16];                                                     \
        _Pragma("unroll")                                                   \
        for (int j_ = 0; j_ < 16; ++j_)                                     \
            acc_[j_] = (BIASPTR) ? (BIASPTR)[h0_ + j_] : 0.f;               \
        _Pragma("unroll 2")                                                 \
        for (int kp_ = 0; kp_ < 32; ++kp_) {                                \
            const u32 zw_ = Zs[tid * ZROW + kp_];                           \
            const float s0_ = bflo(zw_), s1_ = bfhi(zw_);                   \
            const float4* w0_ = (const float4*)&(WPTR)[(2*kp_) * 64 + h0_]; \
            const float4* w1_ = (const float4*)&(WPTR)[(2*kp_+1)*64 + h0_]; \
            _Pragma("unroll")                                               \
            for (int q_ = 0; q_ < 4; ++q_) {                                \
                const float4 a_ = w0_[q_];                                  \
                acc_[4*q_]   = fmaf(s0_, a_.x, acc_[4*q_]);                 \
                acc_[4*q_+1] = fmaf(s0_, a_.y, acc_[4*q_+1]);               \
                acc_[4*q_+2] = fmaf(s0_, a_.z, acc_[4*q_+2]);               \
                acc_[4*q_+3] = fmaf(s0_, a_.w, acc_[4*q_+3]);               \
                const float4 b_ = w1_[q_];                                  \
                acc_[4*q_]   = fmaf(s1_, b_.x, acc_[4*q_]);                 \
                acc_[4*q_+1] = fmaf(s1_, b_.y, acc_[4*q_+1]);               \
                acc_[4*q_+2] = fmaf(s1_, b_.z, acc_[4*q_+2]);               \
                acc_[4*q_+3] = fmaf(s1_, b_.w, acc_[4*q_+3]);               \
            }                                                               \
        }                                                                   \
        _Pragma("unroll")                                                   \
        for (int j_ = 0; j_ < 8; ++j_) {                                    \
            float e0_ = acc_[2*j_], e1_ = acc_[2*j_+1];                     \
            if (DO_RELU) { e0_ = fmaxf(e0_, 0.f); e1_ = fmaxf(e1_, 0.f); }  \
            osum_ += e0_ + e1_;                                             \
            osq_ = fmaf(e0_, e0_, osq_); osq_ = fmaf(e1_, e1_, osq_);       \
            (OUTP)[hc_*8 + j_] = pack2(e0_, e1_);                           \
        }                                                                   \
    }                                                                       \
    (OSUM) = osum_; (OSQ) = osq_;                                           \
} while (0)

// in-place LN on packed OUTP using f32 stats
#define LN_APPLY(OUTP, SUM, SQ, GP, BP) do {                                \
    const float mu_ = (SUM) * 0.015625f;                                    \
    const float rs_ = rsqrtf((SQ) * 0.015625f - mu_*mu_ + EPS);             \
    _Pragma("unroll")                                                       \
    for (int c_ = 0; c_ < 32; ++c_) {                                       \
        const u32 w_ = (OUTP)[c_];                                          \
        const float e0_ = (bflo(w_) - mu_) * rs_ * (GP)[2*c_]   + (BP)[2*c_];   \
        const float e1_ = (bfhi(w_) - mu_) * rs_ * (GP)[2*c_+1] + (BP)[2*c_+1]; \
        (OUTP)[c_] = pack2(e0_, e1_);                                       \
    }                                                                       \
} while (0)

__global__ __launch_bounds__(256) void phase1_kernel(
    const float* __restrict__ z,
    const float* __restrict__ root_w, const float* __restrict__ root_b,
    const float* __restrict__ wt1, const float* __restrict__ lin1_b,
    const float* __restrict__ wt2, const float* __restrict__ lin2_b,
    const float* __restrict__ bil_w,
    const float* __restrict__ norm_g, const float* __restrict__ norm_b,
    u16* __restrict__ T1, u16* __restrict__ T2, int nnodes)
{
    __shared__ u32 Zs[256 * ZROW];       // 33.8 KB; strictly per-thread rows

    const int tid  = threadIdx.x;
    const int node = blockIdx.x * 256 + tid;

    // ---- stage: load row, LN (f32), pack bf16 into own LDS row ----
    {
        float r[64];
        if (node == 0) {
#pragma unroll
            for (int q = 0; q < 16; ++q) {
                const float4 a = *(const float4*)&root_w[4*q];
                const float4 b = *(const float4*)&root_b[4*q];
                r[4*q] = a.x + b.x; r[4*q+1] = a.y + b.y;
                r[4*q+2] = a.z + b.z; r[4*q+3] = a.w + b.w;
            }
        } else if (node < nnodes) {
            const float4* zp = (const float4*)(z + (size_t)(node - 1) * HDIM);
#pragma unroll
            for (int q = 0; q < 16; ++q) {
                const float4 v = zp[q];
                r[4*q] = v.x; r[4*q+1] = v.y; r[4*q+2] = v.z; r[4*q+3] = v.w;
            }
        } else {
#pragma unroll
            for (int k = 0; k < 64; ++k) r[k] = 0.f;
        }
        float sA=0.f,sB=0.f,sC=0.f,sD=0.f, qA=0.f,qB=0.f,qC=0.f,qD=0.f;
#pragma unroll
        for (int k = 0; k < 64; k += 4) {
            sA += r[k];   qA = fmaf(r[k],   r[k],   qA);
            sB += r[k+1]; qB = fmaf(r[k+1], r[k+1], qB);
            sC += r[k+2]; qC = fmaf(r[k+2], r[k+2], qC);
            sD += r[k+3]; qD = fmaf(r[k+3], r[k+3], qD);
        }
        const float mu = (sA+sB+sC+sD) * 0.015625f;
        const float rs = rsqrtf((qA+qB+qC+qD) * 0.015625f - mu*mu + EPS);
#pragma unroll
        for (int c = 0; c < 32; c += 2) {       // 4 values per iter
            const float4 g4 = *(const float4*)&norm_g[2*c];
            const float4 b4 = *(const float4*)&norm_b[2*c];
            const float e0 = (r[2*c]   - mu) * rs * g4.x + b4.x;
            const float e1 = (r[2*c+1] - mu) * rs * g4.y + b4.y;
            const float e2 = (r[2*c+2] - mu) * rs * g4.z + b4.z;
            const float e3 = (r[2*c+3] - mu) * rs * g4.w + b4.w;
            Zs[tid * ZROW + c]     = pack2(e0, e1);
            Zs[tid * ZROW + c + 1] = pack2(e2, e3);
        }
    }
    // no barrier needed: each thread only ever touches its own row

    u32 xp[32];
    float sum, sq;

    // ---- x2 = LN(relu(zz @ W2^T + b2)) -> T2 ----
    MATMUL(wt2, lin2_b, true, xp, sum, sq);
    LN_APPLY(xp, sum, sq, norm_g, norm_b);
    if (node < nnodes) {
        uint4* dst = (uint4*)(T2 + (size_t)node * HDIM);
#pragma unroll
        for (int q = 0; q < 8; ++q)
            dst[q] = make_uint4(xp[4*q], xp[4*q+1], xp[4*q+2], xp[4*q+3]);
    }

    // ---- x1 = LN(relu(zz @ W1^T + b1)) -> back into LDS row ----
    MATMUL(wt1, lin1_b, true, xp, sum, sq);
    LN_APPLY(xp, sum, sq, norm_g, norm_b);
#pragma unroll
    for (int c = 0; c < 32; ++c) Zs[tid * ZROW + c] = xp[c];

    // ---- t = x1 @ B -> T1 (bil_w row-major [h][g]: no transpose needed) ----
    MATMUL(bil_w, (const float*)nullptr, false, xp, sum, sq);
    if (node < nnodes) {
        uint4* dst = (uint4*)(T1 + (size_t)node * HDIM);
#pragma unroll
        for (int q = 0; q < 8; ++q)
            dst[q] = make_uint4(xp[4*q], xp[4*q+1], xp[4*q+2], xp[4*q+3]);
    }
}

// ---------- phase 2: per-edge gather + 64-dot ----------
__global__ __launch_bounds__(256) void phase2_kernel(
    const int* __restrict__ arcs,
    const u16* __restrict__ T1, const u16* __restrict__ T2,
    const float* __restrict__ bil_b,
    float* __restrict__ out, int E)
{
    const int tid = blockIdx.x * 256 + threadIdx.x;
    const int e = tid >> 3;
    if (e >= E) return;
    const int l8 = tid & 7;

    const int i0 = arcs[2 * e];
    const int i1 = arcs[2 * e + 1];

    const uint4* p1 = (const uint4*)(T1 + (size_t)i0 * HDIM) + l8;
    const uint4* p2 = (const uint4*)(T2 + (size_t)i1 * HDIM) + l8;
    uint4 u = *p1;
    uint4 v = *p2;

    float s = 0.f;
    {
        u32 ua[4] = {u.x, u.y, u.z, u.w};
        u32 va[4] = {v.x, v.y, v.z, v.w};
#pragma unroll
        for (int i = 0; i < 4; ++i) {
            s = fmaf(bflo(ua[i]), bflo(va[i]), s);
            s = fmaf(bfhi(ua[i]), bfhi(va[i]), s);
        }
    }
    s += __shfl_xor(s, 1, 64);
    s += __shfl_xor(s, 2, 64);
    s += __shfl_xor(s, 4, 64);
    if (l8 == 0) out[e] = s + bil_b[0];
}

// ---------- fallback: per-edge full recompute (if ws too small) ----------
__device__ __forceinline__ float lnorm_w(float v, float g, float b) {
    float mu = wave_sum64(v) * 0.015625f;
    float d  = v - mu;
    float var = wave_sum64(d * d) * 0.015625f;
    return d * rsqrtf(var + EPS) * g + b;
}

__global__ __launch_bounds__(256) void edge_direct_kernel(
    const float* __restrict__ z, const int* __restrict__ arcs,
    const float* __restrict__ root_w, const float* __restrict__ root_b,
    const float* __restrict__ lin1_w, const float* __restrict__ lin1_b,
    const float* __restrict__ lin2_w, const float* __restrict__ lin2_b,
    const float* __restrict__ bil_w, const float* __restrict__ bil_b,
    const float* __restrict__ norm_g, const float* __restrict__ norm_b,
    float* __restrict__ out, int E, int nnodes)
{
    __shared__ float W1t[4096], W2t[4096], Bs[4096];
    const int tid = threadIdx.x;
    for (int i = tid; i < 4096; i += 256) {
        int h = i >> 6, k = i & 63;
        W1t[(k << 6) | h] = lin1_w[i];
        W2t[(k << 6) | h] = lin2_w[i];
        Bs[i] = bil_w[i];
    }
    __syncthreads();

    const int lane = tid & 63;
    const float g  = norm_g[lane], bt = norm_b[lane];
    const float b1 = lin1_b[lane], b2 = lin2_b[lane];
    const float rootv = root_w[lane] + root_b[lane];

    const int gwave = (blockIdx.x * 256 + tid) >> 6;
    const int nwaves = (gridDim.x * 256) >> 6;

    for (int e = gwave; e < E; e += nwaves) {
        int i0 = arcs[2 * e], i1 = arcs[2 * e + 1];
        float v0 = (i0 == 0) ? rootv : z[(size_t)(i0 - 1) * HDIM + lane];
        float v1 = (i1 == 0) ? rootv : z[(size_t)(i1 - 1) * HDIM + lane];
        float l0 = lnorm_w(v0, g, bt);
        float l1 = lnorm_w(v1, g, bt);
        float a1 = 0.f, a2 = 0.f;
#pragma unroll
        for (int k = 0; k < 64; ++k) {
            a1 = fmaf(bcast(l0, k), W1t[(k << 6) | lane], a1);
            a2 = fmaf(bcast(l1, k), W2t[(k << 6) | lane], a2);
        }
        float x1 = lnorm_w(fmaxf(a1 + b1, 0.f), g, bt);
        float x2 = lnorm_w(fmaxf(a2 + b2, 0.f), g, bt);
        float w1 = 0.f;
#pragma unroll
        for (int h = 0; h < 64; ++h)
            w1 = fmaf(bcast(x1, h), Bs[(h << 6) | lane], w1);
        float sc = wave_sum64(w1 * x2);
        if (lane == 0) out[e] = sc + bil_b[0];
    }
}

// ---------- launch ----------
extern "C" void kernel_launch(void* const* d_in, const int* in_sizes, int n_in,
                              void* d_out, int out_size, void* d_ws, size_t ws_size,
                              hipStream_t stream) {
    const float* z      = (const float*)d_in[0];
    const int*   arcs   = (const int*)  d_in[1];
    const float* root_w = (const float*)d_in[2];
    const float* root_b = (const float*)d_in[3];
    const float* lin1_w = (const float*)d_in[4];
    const float* lin1_b = (const float*)d_in[5];
    const float* lin2_w = (const float*)d_in[6];
    const float* lin2_b = (const float*)d_in[7];
    const float* bil_w  = (const float*)d_in[8];
    const float* bil_b  = (const float*)d_in[9];
    const float* norm_g = (const float*)d_in[10];
    const float* norm_b = (const float*)d_in[11];
    float* out = (float*)d_out;

    const int E      = in_sizes[1] / 2;
    const int nnodes = in_sizes[0] / HDIM + 1;

    const size_t tbl  = (size_t)nnodes * HDIM * sizeof(u16);
    const size_t need = 2 * tbl + 2 * 4096 * sizeof(float);

    if (ws_size >= need) {
        u16*   T1  = (u16*)d_ws;
        u16*   T2  = (u16*)((char*)d_ws + tbl);
        float* wt1 = (float*)((char*)d_ws + 2 * tbl);
        float* wt2 = wt1 + 4096;

        transpose_w_kernel<<<1, 256, 0, stream>>>(lin1_w, lin2_w, wt1, wt2);

        const int blocks1 = (nnodes + 255) / 256;
        phase1_kernel<<<blocks1, 256, 0, stream>>>(
            z, root_w, root_b, wt1, lin1_b, wt2, lin2_b,
            bil_w, norm_g, norm_b, T1, T2, nnodes);

        const long long thr2 = (long long)E * 8;
        const int blocks2 = (int)((thr2 + 255) / 256);
        phase2_kernel<<<blocks2, 256, 0, stream>>>(arcs, T1, T2, bil_b, out, E);
    } else {
        edge_direct_kernel<<<8192, 256, 0, stream>>>(
            z, arcs, root_w, root_b, lin1_w, lin1_b, lin2_w, lin2_b,
            bil_w, bil_b, norm_g, norm_b, out, E, nnodes);
    }
}

// Round 8
// 131.685 us; speedup vs baseline: 7.8304x; 1.3926x over previous
//
#include <hip/hip_runtime.h>
#include <hip/hip_bf16.h>

typedef unsigned short u16;
typedef unsigned int u32;

typedef float f32x4 __attribute__((ext_vector_type(4)));
typedef short bf16x8 __attribute__((ext_vector_type(8)));

#define HDIM 64
#define EPS 1e-5f
#define XROW 68      // u16 stride per LDS row (8B-aligned, bank-spread)

// ---------- helpers ----------

__device__ __forceinline__ float wave_sum64(float v) {
    v += __shfl_xor(v, 1, 64);
    v += __shfl_xor(v, 2, 64);
    v += __shfl_xor(v, 4, 64);
    v += __shfl_xor(v, 8, 64);
    v += __shfl_xor(v, 16, 64);
    v += __shfl_xor(v, 32, 64);
    return v;
}

__device__ __forceinline__ float bcast(float v, int k) {
    return __int_as_float(__builtin_amdgcn_readlane(__float_as_int(v), k));
}

// round-to-nearest-even f32 -> bf16 bits
__device__ __forceinline__ u16 f2bf(float f) {
    u32 u = __float_as_uint(f);
    u32 r = (u + 0x7fffu + ((u >> 16) & 1u)) >> 16;
    return (u16)r;
}

__device__ __forceinline__ float bflo(u32 w) { return __uint_as_float(w << 16); }
__device__ __forceinline__ float bfhi(u32 w) { return __uint_as_float(w & 0xffff0000u); }

// ---------- prep: bf16 weight copies (bil_w transposed) ----------
__global__ __launch_bounds__(256) void prep_kernel(
    const float* __restrict__ lin1_w, const float* __restrict__ lin2_w,
    const float* __restrict__ bil_w,
    u16* __restrict__ w1bf, u16* __restrict__ w2bf, u16* __restrict__ btbf)
{
    const int tid = threadIdx.x;
    for (int i = tid; i < 4096; i += 256) {
        w1bf[i] = f2bf(lin1_w[i]);            // row-major [h][k]
        w2bf[i] = f2bf(lin2_w[i]);
        const int g = i >> 6, h = i & 63;
        btbf[i] = f2bf(bil_w[h * 64 + g]);    // btbf[g][h] = bil_w[h][g]
    }
}

// ---------- MFMA fragment loaders ----------
// A (M=16 x K=32): lane l holds row l%16, k = 8*(l>>4)+i (i=0..7)  [m92-verified]
__device__ __forceinline__ bf16x8 load_afrag(const u16* Xs, int l, int s) {
    const int row = l & 15;
    const int k0  = 8 * (l >> 4) + 32 * s;
    union { uint2 u[2]; bf16x8 f; } c;
    c.u[0] = *(const uint2*)&Xs[row * XROW + k0];
    c.u[1] = *(const uint2*)&Xs[row * XROW + k0 + 4];
    return c.f;
}

// B (K=32 x N=16): lane l holds col l%16, k = 8*(l>>4)+i.
// B[k][n] = W[n][k] with W row-major [n][k] -> 8 contiguous elements of row n.
__device__ __forceinline__ bf16x8 load_bfrag(const u16* __restrict__ W,
                                             int l, int t, int s) {
    const int n  = (l & 15) + 16 * t;
    const int k0 = 8 * (l >> 4) + 32 * s;
    return *(const bf16x8*)&W[n * 64 + k0];
}

// relu(acc + bias) then LN across h (4 tiles x 4 regs, 16-lane reduce).
// C/D layout: col = l&15 (+16t), row(node) = (l>>4)*4 + reg   [m89-verified]
__device__ __forceinline__ void relu_ln_acc(f32x4* acc, const float* biasv,
                                            const float* gv, const float* bvv) {
    float s[4] = {0.f,0.f,0.f,0.f}, q[4] = {0.f,0.f,0.f,0.f};
#pragma unroll
    for (int t = 0; t < 4; ++t)
#pragma unroll
        for (int j = 0; j < 4; ++j) {
            float v = fmaxf(acc[t][j] + biasv[t], 0.f);
            acc[t][j] = v;
            s[j] += v; q[j] = fmaf(v, v, q[j]);
        }
#pragma unroll
    for (int j = 0; j < 4; ++j) {
#pragma unroll
        for (int m = 1; m < 16; m <<= 1) {
            s[j] += __shfl_xor(s[j], m, 64);
            q[j] += __shfl_xor(q[j], m, 64);
        }
        const float mu = s[j] * 0.015625f;
        const float rs = rsqrtf(q[j] * 0.015625f - mu * mu + EPS);
#pragma unroll
        for (int t = 0; t < 4; ++t)
            acc[t][j] = (acc[t][j] - mu) * rs * gv[t] + bvv[t];
    }
}

// scatter acc (bf16) into LDS rows [node][h]
__device__ __forceinline__ void acc_to_lds(u16* Y, const f32x4* acc, int l) {
    const int hcol = l & 15;
#pragma unroll
    for (int j = 0; j < 4; ++j) {
        const int row = (l >> 4) * 4 + j;
#pragma unroll
        for (int t = 0; t < 4; ++t)
            Y[row * XROW + hcol + 16 * t] = f2bf(acc[t][j]);
    }
}

// coalesced copy of 16 LDS rows (64 bf16 each) to global table
__device__ __forceinline__ void lds_to_global(u16* __restrict__ T, const u16* Y,
                                              int l, int n0, int nnodes) {
    const int row  = l >> 2;
    const int node = n0 + row;
    if (node < nnodes) {
        const int co = (l & 3) * 16;
        uint2 p0 = *(const uint2*)&Y[row * XROW + co];
        uint2 p1 = *(const uint2*)&Y[row * XROW + co + 4];
        uint2 p2 = *(const uint2*)&Y[row * XROW + co + 8];
        uint2 p3 = *(const uint2*)&Y[row * XROW + co + 12];
        uint4* d = (uint4*)(T + (size_t)node * HDIM + co);
        d[0] = make_uint4(p0.x, p0.y, p1.x, p1.y);
        d[1] = make_uint4(p2.x, p2.y, p3.x, p3.y);
    }
}

// ---------- phase 1: MFMA per-node transform -> bf16 tables ----------
// One wave per 16 nodes; wave-private LDS (no barriers).
__global__ __launch_bounds__(256) void phase1_kernel(
    const float* __restrict__ z,
    const float* __restrict__ root_w, const float* __restrict__ root_b,
    const u16* __restrict__ w1bf, const float* __restrict__ lin1_b,
    const u16* __restrict__ w2bf, const float* __restrict__ lin2_b,
    const u16* __restrict__ btbf,
    const float* __restrict__ norm_g, const float* __restrict__ norm_b,
    u16* __restrict__ T1, u16* __restrict__ T2, int nnodes)
{
    __shared__ u16 XsAll[4][16 * XROW];
    __shared__ u16 YsAll[4][16 * XROW];

    const int tid = threadIdx.x;
    const int wid = tid >> 6;
    const int l   = tid & 63;
    u16* Xs = XsAll[wid];
    u16* Ys = YsAll[wid];

    const int n0 = (blockIdx.x * 4 + wid) * 16;

    // ---- stage: load z rows (4 lanes/row), LN, pack bf16 -> Xs ----
    {
        const int row  = l >> 2;
        const int node = n0 + row;
        const int c0   = (l & 3) * 16;
        float r[16];
        if (node == 0) {
#pragma unroll
            for (int qq = 0; qq < 4; ++qq) {
                const float4 a = *(const float4*)&root_w[c0 + 4*qq];
                const float4 b = *(const float4*)&root_b[c0 + 4*qq];
                r[4*qq] = a.x + b.x; r[4*qq+1] = a.y + b.y;
                r[4*qq+2] = a.z + b.z; r[4*qq+3] = a.w + b.w;
            }
        } else if (node < nnodes) {
            const float4* zp = (const float4*)(z + (size_t)(node - 1) * HDIM + c0);
#pragma unroll
            for (int qq = 0; qq < 4; ++qq) {
                const float4 v = zp[qq];
                r[4*qq] = v.x; r[4*qq+1] = v.y; r[4*qq+2] = v.z; r[4*qq+3] = v.w;
            }
        } else {
#pragma unroll
            for (int k = 0; k < 16; ++k) r[k] = 0.f;
        }
        float s = 0.f, sq = 0.f;
#pragma unroll
        for (int k = 0; k < 16; ++k) { s += r[k]; sq = fmaf(r[k], r[k], sq); }
        s  += __shfl_xor(s, 1, 64);  sq += __shfl_xor(sq, 1, 64);
        s  += __shfl_xor(s, 2, 64);  sq += __shfl_xor(sq, 2, 64);
        const float mu = s * 0.015625f;
        const float rs = rsqrtf(sq * 0.015625f - mu * mu + EPS);
        u16 tmp[16];
#pragma unroll
        for (int qq = 0; qq < 4; ++qq) {
            const float4 g4 = *(const float4*)&norm_g[c0 + 4*qq];
            const float4 b4 = *(const float4*)&norm_b[c0 + 4*qq];
            tmp[4*qq]   = f2bf((r[4*qq]   - mu) * rs * g4.x + b4.x);
            tmp[4*qq+1] = f2bf((r[4*qq+1] - mu) * rs * g4.y + b4.y);
            tmp[4*qq+2] = f2bf((r[4*qq+2] - mu) * rs * g4.z + b4.z);
            tmp[4*qq+3] = f2bf((r[4*qq+3] - mu) * rs * g4.w + b4.w);
        }
        u16* dst = &Xs[row * XROW + c0];
#pragma unroll
        for (int j = 0; j < 4; ++j)
            *(uint2*)&dst[4*j] = *(const uint2*)&tmp[4*j];
    }

    // ---- per-lane constants ----
    const int hcol = l & 15;
    float gv[4], bv[4], b1v[4], b2v[4];
#pragma unroll
    for (int t = 0; t < 4; ++t) {
        gv[t]  = norm_g[hcol + 16*t];
        bv[t]  = norm_b[hcol + 16*t];
        b1v[t] = lin1_b[hcol + 16*t];
        b2v[t] = lin2_b[hcol + 16*t];
    }

    // ---- A fragments from LN'd zz ----
    bf16x8 a0 = load_afrag(Xs, l, 0);
    bf16x8 a1 = load_afrag(Xs, l, 1);

    // ---- y2 = zz@W2^T, y1 = zz@W1^T (both while zz frags live) ----
    f32x4 acc2[4], acc1[4];
#pragma unroll
    for (int t = 0; t < 4; ++t) {
        f32x4 c = {0.f, 0.f, 0.f, 0.f};
        c = __builtin_amdgcn_mfma_f32_16x16x32_bf16(a0, load_bfrag(w2bf, l, t, 0), c, 0, 0, 0);
        c = __builtin_amdgcn_mfma_f32_16x16x32_bf16(a1, load_bfrag(w2bf, l, t, 1), c, 0, 0, 0);
        acc2[t] = c;
    }
#pragma unroll
    for (int t = 0; t < 4; ++t) {
        f32x4 c = {0.f, 0.f, 0.f, 0.f};
        c = __builtin_amdgcn_mfma_f32_16x16x32_bf16(a0, load_bfrag(w1bf, l, t, 0), c, 0, 0, 0);
        c = __builtin_amdgcn_mfma_f32_16x16x32_bf16(a1, load_bfrag(w1bf, l, t, 1), c, 0, 0, 0);
        acc1[t] = c;
    }

    // ---- x2 -> T2 ----
    relu_ln_acc(acc2, b2v, gv, bv);
    acc_to_lds(Ys, acc2, l);
    lds_to_global(T2, Ys, l, n0, nnodes);

    // ---- x1 -> Xs (zz dead) ----
    relu_ln_acc(acc1, b1v, gv, bv);
    acc_to_lds(Xs, acc1, l);
    a0 = load_afrag(Xs, l, 0);
    a1 = load_afrag(Xs, l, 1);

    // ---- t = x1 @ bil_w -> T1 (no bias/relu/LN) ----
    f32x4 acc3[4];
#pragma unroll
    for (int t = 0; t < 4; ++t) {
        f32x4 c = {0.f, 0.f, 0.f, 0.f};
        c = __builtin_amdgcn_mfma_f32_16x16x32_bf16(a0, load_bfrag(btbf, l, t, 0), c, 0, 0, 0);
        c = __builtin_amdgcn_mfma_f32_16x16x32_bf16(a1, load_bfrag(btbf, l, t, 1), c, 0, 0, 0);
        acc3[t] = c;
    }
    acc_to_lds(Ys, acc3, l);
    lds_to_global(T1, Ys, l, n0, nnodes);
}

// ---------- phase 2: per-edge gather + 64-dot ----------
__global__ __launch_bounds__(256) void phase2_kernel(
    const int* __restrict__ arcs,
    const u16* __restrict__ T1, const u16* __restrict__ T2,
    const float* __restrict__ bil_b,
    float* __restrict__ out, int E)
{
    const int tid = blockIdx.x * 256 + threadIdx.x;
    const int e = tid >> 3;
    if (e >= E) return;
    const int l8 = tid & 7;

    const int i0 = arcs[2 * e];
    const int i1 = arcs[2 * e + 1];

    const uint4* p1 = (const uint4*)(T1 + (size_t)i0 * HDIM) + l8;
    const uint4* p2 = (const uint4*)(T2 + (size_t)i1 * HDIM) + l8;
    uint4 u = *p1;
    uint4 v = *p2;

    float s = 0.f;
    {
        u32 ua[4] = {u.x, u.y, u.z, u.w};
        u32 va[4] = {v.x, v.y, v.z, v.w};
#pragma unroll
        for (int i = 0; i < 4; ++i) {
            s = fmaf(bflo(ua[i]), bflo(va[i]), s);
            s = fmaf(bfhi(ua[i]), bfhi(va[i]), s);
        }
    }
    s += __shfl_xor(s, 1, 64);
    s += __shfl_xor(s, 2, 64);
    s += __shfl_xor(s, 4, 64);
    if (l8 == 0) out[e] = s + bil_b[0];
}

// ---------- fallback: per-edge full recompute (if ws too small) ----------
__device__ __forceinline__ float lnorm_w(float v, float g, float b) {
    float mu = wave_sum64(v) * 0.015625f;
    float d  = v - mu;
    float var = wave_sum64(d * d) * 0.015625f;
    return d * rsqrtf(var + EPS) * g + b;
}

__global__ __launch_bounds__(256) void edge_direct_kernel(
    const float* __restrict__ z, const int* __restrict__ arcs,
    const float* __restrict__ root_w, const float* __restrict__ root_b,
    const float* __restrict__ lin1_w, const float* __restrict__ lin1_b,
    const float* __restrict__ lin2_w, const float* __restrict__ lin2_b,
    const float* __restrict__ bil_w, const float* __restrict__ bil_b,
    const float* __restrict__ norm_g, const float* __restrict__ norm_b,
    float* __restrict__ out, int E, int nnodes)
{
    __shared__ float W1t[4096], W2t[4096], Bs[4096];
    const int tid = threadIdx.x;
    for (int i = tid; i < 4096; i += 256) {
        int h = i >> 6, k = i & 63;
        W1t[(k << 6) | h] = lin1_w[i];
        W2t[(k << 6) | h] = lin2_w[i];
        Bs[i] = bil_w[i];
    }
    __syncthreads();

    const int lane = tid & 63;
    const float g  = norm_g[lane], bt = norm_b[lane];
    const float b1 = lin1_b[lane], b2 = lin2_b[lane];
    const float rootv = root_w[lane] + root_b[lane];

    const int gwave = (blockIdx.x * 256 + tid) >> 6;
    const int nwaves = (gridDim.x * 256) >> 6;

    for (int e = gwave; e < E; e += nwaves) {
        int i0 = arcs[2 * e], i1 = arcs[2 * e + 1];
        float v0 = (i0 == 0) ? rootv : z[(size_t)(i0 - 1) * HDIM + lane];
        float v1 = (i1 == 0) ? rootv : z[(size_t)(i1 - 1) * HDIM + lane];
        float l0 = lnorm_w(v0, g, bt);
        float l1 = lnorm_w(v1, g, bt);
        float a1 = 0.f, a2 = 0.f;
#pragma unroll
        for (int k = 0; k < 64; ++k) {
            a1 = fmaf(bcast(l0, k), W1t[(k << 6) | lane], a1);
            a2 = fmaf(bcast(l1, k), W2t[(k << 6) | lane], a2);
        }
        float x1 = lnorm_w(fmaxf(a1 + b1, 0.f), g, bt);
        float x2 = lnorm_w(fmaxf(a2 + b2, 0.f), g, bt);
        float w1 = 0.f;
#pragma unroll
        for (int h = 0; h < 64; ++h)
            w1 = fmaf(bcast(x1, h), Bs[(h << 6) | lane], w1);
        float sc = wave_sum64(w1 * x2);
        if (lane == 0) out[e] = sc + bil_b[0];
    }
}

// ---------- launch ----------
extern "C" void kernel_launch(void* const* d_in, const int* in_sizes, int n_in,
                              void* d_out, int out_size, void* d_ws, size_t ws_size,
                              hipStream_t stream) {
    const float* z      = (const float*)d_in[0];
    const int*   arcs   = (const int*)  d_in[1];
    const float* root_w = (const float*)d_in[2];
    const float* root_b = (const float*)d_in[3];
    const float* lin1_w = (const float*)d_in[4];
    const float* lin1_b = (const float*)d_in[5];
    const float* lin2_w = (const float*)d_in[6];
    const float* lin2_b = (const float*)d_in[7];
    const float* bil_w  = (const float*)d_in[8];
    const float* bil_b  = (const float*)d_in[9];
    const float* norm_g = (const float*)d_in[10];
    const float* norm_b = (const float*)d_in[11];
    float* out = (float*)d_out;

    const int E      = in_sizes[1] / 2;
    const int nnodes = in_sizes[0] / HDIM + 1;

    const size_t tbl  = (size_t)nnodes * HDIM * sizeof(u16);
    const size_t need = 2 * tbl + 3 * 4096 * sizeof(u16);

    if (ws_size >= need) {
        u16* T1   = (u16*)d_ws;
        u16* T2   = (u16*)((char*)d_ws + tbl);
        u16* w1bf = (u16*)((char*)d_ws + 2 * tbl);
        u16* w2bf = w1bf + 4096;
        u16* btbf = w2bf + 4096;

        prep_kernel<<<1, 256, 0, stream>>>(lin1_w, lin2_w, bil_w, w1bf, w2bf, btbf);

        const int blocks1 = (nnodes + 63) / 64;
        phase1_kernel<<<blocks1, 256, 0, stream>>>(
            z, root_w, root_b, w1bf, lin1_b, w2bf, lin2_b, btbf,
            norm_g, norm_b, T1, T2, nnodes);

        const long long thr2 = (long long)E * 8;
        const int blocks2 = (int)((thr2 + 255) / 256);
        phase2_kernel<<<blocks2, 256, 0, stream>>>(arcs, T1, T2, bil_b, out, E);
    } else {
        edge_direct_kernel<<<8192, 256, 0, stream>>>(
            z, arcs, root_w, root_b, lin1_w, lin1_b, lin2_w, lin2_b,
            bil_w, bil_b, norm_g, norm_b, out, E, nnodes);
    }
}